// Round 9
// baseline (386.031 us; speedup 1.0000x reference)
//
#include <hip/hip_runtime.h>
#include <math.h>

#define F_ 48
#define C_ 128
#define HW 16384
#define SCALE_C 0.999f
#define TPB 256      // setup kernels
#define MW 256       // main kernel: 4 waves/block, 8 blocks/CU

typedef __attribute__((ext_vector_type(4))) float floatx4;
typedef __attribute__((ext_vector_type(8))) _Float16 half8;
typedef __attribute__((ext_vector_type(4))) _Float16 half4;

// ---- ws layout ----
// ushort region:
//   P1 frags (f16): [mtile(24)][ks(4)][lane(64)][j(8)] = 49152 ushorts
//     even mtile = Wf rows (v), odd mtile = (Qeq.Wf) rows (y), paired per f-group
//   P2 frags (f16): [cmt(8)][ks(6)][lane(64)][j(8)] = 24576 ushorts at 49152
//     (Wf^T only; gcc matvec done in VALU)
// float region at float offset 36864 (byte 147456):
#define P1_U 0
#define P2_U 49152
#define QEQN_F 36864              // [48][32]: [0..15]=Qeq[l][g], [16..31]=SCALE*Qm[g][l]
#define MISC_F (QEQN_F + 1536)    // eps_e, invden
#define SINV_F (MISC_F + 2)       // [2][48] 1/scaling
#define SLAM_F (SINV_F + 96)      // [2][48] lamb_e*scaling

// ---------------- setup: math (1 block, tiny) ----------------
__global__ void setup_math(const float* __restrict__ sigma,
                           const float* __restrict__ Qp,
                           const float* __restrict__ taus_p,
                           const float* __restrict__ lamb,
                           const float* __restrict__ eps_om,
                           const float* __restrict__ mw1, const float* __restrict__ mb1,
                           const float* __restrict__ mw2, const float* __restrict__ mb2,
                           const float* __restrict__ mw3, const float* __restrict__ mb3,
                           float* __restrict__ wsf)
{
    const int tid = threadIdx.x;
    if (tid < F_) {
        const int f = tid;
        float Qm[4][4];
        for (int g = 0; g < 4; ++g) {
            float s = 0.f;
            for (int l = 0; l < 4; ++l) s += fabsf(Qp[f * 16 + g * 4 + l]);
            float d = fmaxf(s, 1.0f);
            for (int l = 0; l < 4; ++l) Qm[g][l] = Qp[f * 16 + g * 4 + l] / d;
        }
        double A[4][4];
        for (int i = 0; i < 4; ++i)
            for (int j = 0; j < 4; ++j) {
                double s = 0.0;
                for (int g = 0; g < 4; ++g) s += (double)Qm[g][i] * (double)Qm[g][j];
                A[i][j] = s;
            }
        double M[4][4];
        for (int i = 0; i < 4; ++i) for (int j = 0; j < 4; ++j) M[i][j] = A[i][j];
        for (int it = 0; it < 30; ++it) {
            double T[4][4]; double mx = 0.0;
            for (int i = 0; i < 4; ++i)
                for (int j = 0; j < 4; ++j) {
                    double s = 0.0;
                    for (int k = 0; k < 4; ++k) s += M[i][k] * M[k][j];
                    T[i][j] = s;
                    double a = fabs(s); if (a > mx) mx = a;
                }
            if (mx < 1e-300) break;
            double inv = 1.0 / mx;
            for (int i = 0; i < 4; ++i) for (int j = 0; j < 4; ++j) M[i][j] = T[i][j] * inv;
        }
        int jb = 0; double bn = -1.0;
        for (int j = 0; j < 4; ++j) {
            double nn = 0.0;
            for (int i = 0; i < 4; ++i) nn += M[i][j] * M[i][j];
            if (nn > bn) { bn = nn; jb = j; }
        }
        double v[4]; for (int i = 0; i < 4; ++i) v[i] = M[i][jb];
        double Av[4];
        for (int i = 0; i < 4; ++i) {
            double s = 0.0;
            for (int j = 0; j < 4; ++j) s += A[i][j] * v[j];
            Av[i] = s;
        }
        double vv = 0.0, vav = 0.0;
        for (int i = 0; i < 4; ++i) { vv += v[i] * v[i]; vav += v[i] * Av[i]; }
        float lamf = (float)((vv > 0.0) ? (vav / vv) : 0.0);
        float tau = expf(fmaxf(taus_p[f], 0.0f));
        float qsv = SCALE_C / tau;
        for (int l = 0; l < 4; ++l)
            for (int g = 0; g < 4; ++g)
                wsf[QEQN_F + f * 32 + l * 4 + g] = qsv * Qm[l][g] / lamf;
        for (int g = 0; g < 4; ++g)
            for (int l = 0; l < 4; ++l)
                wsf[QEQN_F + f * 32 + 16 + g * 4 + l] = SCALE_C * Qm[g][l];
    }
    if (tid >= 48 && tid < 50) {
        const int b = tid - 48;
        float lamb_e = expf(lamb[0]);
        float sg = sigma[b];
        float t = sg * 20.0f - 2.0f;
        float h1[F_], h2[F_];
        for (int j = 0; j < F_; ++j) h1[j] = fmaxf(t * mw1[j] + mb1[j], 0.0f);
        for (int j = 0; j < F_; ++j) {
            float s = mb2[j];
            for (int k = 0; k < F_; ++k) s += h1[k] * mw2[k * F_ + j];
            h2[j] = fmaxf(s, 0.0f);
        }
        for (int j = 0; j < F_; ++j) {
            float s = mb3[j];
            for (int k = 0; k < F_; ++k) s += h2[k] * mw3[k * F_ + j];
            float sc = fmaxf(s * 0.05f + sg, 0.0f) + 1e-9f;
            wsf[SINV_F + b * F_ + j] = 1.0f / sc;
            wsf[SLAM_F + b * F_ + j] = lamb_e * sc;
        }
    }
    if (tid == 50) {
        float lamb_e = expf(lamb[0]);
        float eps_e = expf(eps_om[0]);
        wsf[MISC_F + 0] = eps_e;
        wsf[MISC_F + 1] = 1.0f / (1.0f + lamb_e * (1.0f + eps_e));
    }
}

// ---------------- setup: fragment packing (grid-parallel; AFTER setup_math) ----------------
__global__ void setup_pack(const float* __restrict__ Wf, float* __restrict__ wsf)
{
    unsigned short* wsu = (unsigned short*)wsf;
    const int gtid = blockIdx.x * TPB + threadIdx.x;
    for (int i = gtid; i < 73728; i += gridDim.x * TPB) {
        if (i < 49152) {
            // pass-1 A frags: 24 mtiles. even = Wf (v-rows), odd = Qeq.Wf (y-rows)
            int j = i & 7, lane = (i >> 3) & 63;
            int t = i >> 9;                // 0..95
            int ks = t & 3, mtile = t >> 2;
            int rt = lane & 15, qq = lane >> 4;
            int c = ks * 32 + qq * 8 + j;
            int ft = mtile >> 1;
            int f = ft * 4 + (rt >> 2);
            int gl = rt & 3;
            float w;
            if ((mtile & 1) == 0) {
                w = Wf[(gl * F_ + f) * C_ + c];
            } else {
                w = 0.f;
                for (int g = 0; g < 4; ++g)
                    w += wsf[QEQN_F + f * 32 + gl * 4 + g] * Wf[(g * F_ + f) * C_ + c];
            }
            _Float16 hv = (_Float16)w;
            wsu[P1_U + ((mtile * 4 + ks) * 64 + lane) * 8 + j] = *(unsigned short*)&hv;
        } else {
            // pass-2 A frags: K=192, Wf^T only
            int ii = i - 49152;
            int j = ii & 7, lane = (ii >> 3) & 63;
            int t = ii >> 9;               // 0..47
            int ks = t % 6, cmt = t / 6;
            int m = lane & 15, qq = lane >> 4;
            int cch = cmt * 16 + m;
            int r = ks * 32 + qq * 8 + j;  // 0..191
            int f = r >> 2, g = r & 3;
            float w = Wf[(g * F_ + f) * C_ + cch];
            _Float16 hv = (_Float16)w;
            wsu[P2_U + ((cmt * 6 + ks) * 64 + lane) * 8 + j] = *(unsigned short*)&hv;
        }
    }
}

// Duchi-form l1-ball projection merged with the Moreau output:
//   theta = max(0, max_k (c_k - 1)/k)   (c_k = sum of k largest |v|)
//   o_g   = sign(v_g) * (eps*|v_g| + relu(|v_g| - theta))  ==  eps*v + proj(v)
__device__ __forceinline__ void actmerge(const float v[4], float eps, float o[4]) {
    float a0 = fabsf(v[0]), a1 = fabsf(v[1]), a2 = fabsf(v[2]), a3 = fabsf(v[3]);
    float lo01 = fminf(a0, a1), hi01 = fmaxf(a0, a1);
    float lo23 = fminf(a2, a3), hi23 = fmaxf(a2, a3);
    float c4 = (a0 + a1) + (a2 + a3);
    float mn1 = fminf(lo01, lo23);
    float mn2 = fminf(fmaxf(lo01, lo23), fminf(hi01, hi23));
    float c1 = fmaxf(hi01, hi23);
    float c3 = c4 - mn1;
    float c2 = c3 - mn2;
    float t1 = c1 - 1.0f;
    float t2 = (c2 - 1.0f) * 0.5f;
    float t3 = (c3 - 1.0f) * (1.0f / 3.0f);
    float t4 = (c4 - 1.0f) * 0.25f;
    float theta = fmaxf(fmaxf(fmaxf(t1, t2), fmaxf(t3, t4)), 0.0f);
    float aa[4] = {a0, a1, a2, a3};
#pragma unroll
    for (int g = 0; g < 4; ++g) {
        float r = fmaf(eps, aa[g], fmaxf(aa[g] - theta, 0.0f));
        o[g] = copysignf(r, v[g]);
    }
}

// ---------------- main: 16-pixel tile, 4 waves/block, 2048 blocks ----------------
// Same per-wave job shape as R8 (3 p1 jobs, 2 p2 cmt jobs), but blocks halved:
// barrier domain = 4 waves (was 8), 8 independent blocks/CU (was 4) so
// phase-synchronized load bursts of different blocks interleave.
// launch_bounds(256,8): 8 waves/EU -> 64 VGPR cap, 8 blocks/CU resident.
__global__ __launch_bounds__(MW, 8) void mfoe_main(
    const float* __restrict__ xnoisy,
    const float* __restrict__ wsf,
    float* __restrict__ out,
    const int* __restrict__ n_iter_p)
{
    __shared__ __align__(16) _Float16 sXF[2048];    // [ks(4)][lane(64)][j(8)]
    __shared__ __align__(16) _Float16 sACT[3072];   // [ks(6)][lane(64)][j(8)]
    __shared__ __align__(16) float sQS[F_ * 16];    // SCALE*Qm[g][l] at [f][g*4+l]
    __shared__ __align__(16) float sISL[96];        // [0..47]=invs, [48..95]=slam

    const int tid = threadIdx.x;
    const int lane = tid & 63;
    const int wv = __builtin_amdgcn_readfirstlane(tid >> 6);   // SGPR wave id, 0..3
    const int n = lane & 15;
    const int q = lane >> 4;
    const int blk = blockIdx.x;
    const int b = blk >> 10;                // 1024 blocks per image
    const int pix0 = (blk & 1023) << 4;     // 16 pixels per block

    const float* __restrict__ xin = xnoisy + b * (C_ * HW) + pix0;
    float* __restrict__ oimg = out + b * (C_ * HW) + pix0;
    const unsigned short* __restrict__ wsu = (const unsigned short*)wsf;
    const int niter = *n_iter_p;

    if (niter == 0) {
        for (int i = tid; i < C_ * 16; i += MW) {
            int p = i & 15, c = i >> 4;
            oimg[c * HW + p] = xin[c * HW + p];
        }
        return;
    }

    // stage x -> LDS f16 in fragment order
    for (int i = tid; i < C_ * 16; i += MW) {
        int p = i & 15, c = i >> 4;
        int idx = ((c >> 5) * 64 + ((c >> 3) & 3) * 16 + p) * 8 + (c & 7);
        sXF[idx] = (_Float16)xin[c * HW + p];
    }
    // stage qs (SCALE*Qm) and invs/slam
    for (int i = tid; i < F_ * 16; i += MW)
        sQS[i] = wsf[QEQN_F + (i >> 4) * 32 + 16 + (i & 15)];
    for (int i = tid; i < 96; i += MW) {
        if (i < 48) sISL[i] = wsf[SINV_F + b * F_ + i];
        else        sISL[i] = wsf[SLAM_F + b * F_ + (i - 48)];
    }

    // x_noisy anchor in registers (update layout: cmt = wv*2+jc, pixel n)
    float xnr[8];
#pragma unroll
    for (int jc = 0; jc < 2; ++jc) {
        int cmt = wv * 2 + jc;
#pragma unroll
        for (int l = 0; l < 4; ++l)
            xnr[jc * 4 + l] = xin[(cmt * 16 + q * 4 + l) * HW + n];
    }

    const float eps_e = wsf[MISC_F + 0];
    const float invden = wsf[MISC_F + 1];

    const half8* __restrict__ A1 = (const half8*)wsu;              // P1 frags
    const half8* __restrict__ A2 = (const half8*)(wsu + P2_U);     // P2 frags
    const half8* __restrict__ sXF8 = (const half8*)sXF;
    const half8* __restrict__ sACT8 = (const half8*)sACT;

    for (int it = 0; it < niter; ++it) {
        __syncthreads();   // x ready (and tables on iter 0)
        // ---- pass 1: 12 ft jobs, 3 per wave, low-pressure
#pragma unroll 1
        for (int jj = 0; jj < 3; ++jj) {
            const int ft = wv * 3 + jj;    // 0..11
            floatx4 accv = (floatx4){0.f, 0.f, 0.f, 0.f};
            floatx4 accy = (floatx4){0.f, 0.f, 0.f, 0.f};
#pragma unroll
            for (int ks = 0; ks < 4; ++ks) {
                half8 aV = A1[((ft * 2 + 0) * 4 + ks) * 64 + lane];
                half8 aY = A1[((ft * 2 + 1) * 4 + ks) * 64 + lane];
                half8 bF = sXF8[ks * 64 + lane];
                accv = __builtin_amdgcn_mfma_f32_16x16x32_f16(aV, bF, accv, 0, 0, 0);
                accy = __builtin_amdgcn_mfma_f32_16x16x32_f16(aY, bF, accy, 0, 0, 0);
            }
            // ---- activation: lane owns f = ft*4+q
            const int f = ft * 4 + q;
            const float invs = sISL[f];
            const float slam = sISL[48 + f];
            float qs[16];
#pragma unroll
            for (int k = 0; k < 4; ++k)
                *(floatx4*)&qs[4 * k] = *(const floatx4*)&sQS[f * 16 + 4 * k];
            float v[4] = {accv[0] * invs, accv[1] * invs, accv[2] * invs, accv[3] * invs};
            float y[4] = {accy[0] * invs, accy[1] * invs, accy[2] * invs, accy[3] * invs};
            float uv[4]; actmerge(v, eps_e, uv);    // eps*v + proj(v)
            float m2[4]; actmerge(y, eps_e, m2);    // eps*y + proj(y)
            float a0 = (uv[0] - fmaf(qs[0], m2[0], fmaf(qs[4], m2[1],
                        fmaf(qs[8], m2[2], qs[12] * m2[3])))) * slam;
            float a1 = (uv[1] - fmaf(qs[1], m2[0], fmaf(qs[5], m2[1],
                        fmaf(qs[9], m2[2], qs[13] * m2[3])))) * slam;
            float a2 = (uv[2] - fmaf(qs[2], m2[0], fmaf(qs[6], m2[1],
                        fmaf(qs[10], m2[2], qs[14] * m2[3])))) * slam;
            float a3 = (uv[3] - fmaf(qs[3], m2[0], fmaf(qs[7], m2[1],
                        fmaf(qs[11], m2[2], qs[15] * m2[3])))) * slam;
            half4 av4;
            av4[0] = (_Float16)a0;
            av4[1] = (_Float16)a1;
            av4[2] = (_Float16)a2;
            av4[3] = (_Float16)a3;
            // act rows r = ft*16 + q*4 + l -> frag slot
            int aw = ((ft >> 1) * 64 + ((ft & 1) * 2 + (q >> 1)) * 16 + n) * 8 + (q & 1) * 4;
            *(half4*)&sACT[aw] = av4;
        }
        __syncthreads();   // act ready; all pass-1 x reads done
        // ---- pass 2: 2 cmt jobs per wave, K=192
        floatx4 acc20 = (floatx4){0.f, 0.f, 0.f, 0.f};
        floatx4 acc21 = (floatx4){0.f, 0.f, 0.f, 0.f};
        const int cm0 = wv * 2;
#pragma unroll
        for (int ks = 0; ks < 6; ++ks) {
            half8 bA = sACT8[ks * 64 + lane];
            half8 aF0 = A2[((cm0 + 0) * 6 + ks) * 64 + lane];
            half8 aF1 = A2[((cm0 + 1) * 6 + ks) * 64 + lane];
            acc20 = __builtin_amdgcn_mfma_f32_16x16x32_f16(aF0, bA, acc20, 0, 0, 0);
            acc21 = __builtin_amdgcn_mfma_f32_16x16x32_f16(aF1, bA, acc21, 0, 0, 0);
        }
        // ---- update: thread owns (cmt = wv*2+jc, q); x carried in sXF (f16)
        const bool last = (it == niter - 1);
#pragma unroll
        for (int jc = 0; jc < 2; ++jc) {
            floatx4 acc = jc ? acc21 : acc20;
            int cmt = wv * 2 + jc;
            int cb = cmt * 16 + q * 4;
            int xu = ((cmt >> 1) * 64 + ((cmt & 1) * 2 + (q >> 1)) * 16 + n) * 8 + (q & 1) * 4;
            half4 xo4 = *(const half4*)&sXF[xu];
            half4 nx4;
#pragma unroll
            for (int l = 0; l < 4; ++l) {
                float xo = (float)xo4[l];
                float nx = xo - ((xo - xnr[jc * 4 + l]) + acc[l]) * invden;
                nx4[l] = (_Float16)nx;
                if (last) oimg[(cb + l) * HW + n] = nx;
            }
            *(half4*)&sXF[xu] = nx4;
        }
    }
}

extern "C" void kernel_launch(void* const* d_in, const int* in_sizes, int n_in,
                              void* d_out, int out_size, void* d_ws, size_t ws_size,
                              hipStream_t stream) {
    const float* x_noisy = (const float*)d_in[0];
    const float* sigma   = (const float*)d_in[1];
    const float* Qp      = (const float*)d_in[2];
    const float* taus_p  = (const float*)d_in[3];
    const float* lamb    = (const float*)d_in[4];
    const float* eps_om  = (const float*)d_in[5];
    const float* mw1     = (const float*)d_in[6];
    const float* mb1     = (const float*)d_in[7];
    const float* mw2     = (const float*)d_in[8];
    const float* mb2     = (const float*)d_in[9];
    const float* mw3     = (const float*)d_in[10];
    const float* mb3     = (const float*)d_in[11];
    const float* Wf      = (const float*)d_in[12];
    const int*   n_iter  = (const int*)d_in[13];
    float* out = (float*)d_out;
    float* ws  = (float*)d_ws;

    hipLaunchKernelGGL(setup_math, dim3(1), dim3(64), 0, stream,
                       sigma, Qp, taus_p, lamb, eps_om,
                       mw1, mb1, mw2, mb2, mw3, mb3, ws);
    hipLaunchKernelGGL(setup_pack, dim3(192), dim3(TPB), 0, stream, Wf, ws);
    hipLaunchKernelGGL(mfoe_main, dim3(2048), dim3(MW), 0, stream,
                       x_noisy, ws, out, n_iter);
}

// Round 10
// 278.104 us; speedup vs baseline: 1.3881x; 1.3881x over previous
//
#include <hip/hip_runtime.h>
#include <math.h>

#define F_ 48
#define C_ 128
#define HW 16384
#define SCALE_C 0.999f
#define TPB 256      // setup kernels
#define MW 256       // main kernel: 4 waves/block

typedef __attribute__((ext_vector_type(4))) float floatx4;
typedef __attribute__((ext_vector_type(8))) _Float16 half8;
typedef __attribute__((ext_vector_type(4))) _Float16 half4;

// ---- ws layout ----
// ushort region:
//   P1 frags (f16): [mtile(24)][ks(4)][lane(64)][j(8)] = 49152 ushorts
//     even mtile = Wf rows (v), odd mtile = (Qeq.Wf) rows (y), paired per f-group
//   P2 frags (f16): [cmt(8)][ks(6)][lane(64)][j(8)] = 24576 ushorts at 49152
//     (Wf^T only; gcc matvec done in VALU)
// float region at float offset 36864 (byte 147456):
#define P1_U 0
#define P2_U 49152
#define QEQN_F 36864              // [48][32]: [0..15]=Qeq[l][g], [16..31]=SCALE*Qm[g][l]
#define MISC_F (QEQN_F + 1536)    // eps_e, invden
#define SINV_F (MISC_F + 2)       // [2][48] 1/scaling
#define SLAM_F (SINV_F + 96)      // [2][48] lamb_e*scaling

// ---------------- setup: math (1 block, tiny) ----------------
__global__ void setup_math(const float* __restrict__ sigma,
                           const float* __restrict__ Qp,
                           const float* __restrict__ taus_p,
                           const float* __restrict__ lamb,
                           const float* __restrict__ eps_om,
                           const float* __restrict__ mw1, const float* __restrict__ mb1,
                           const float* __restrict__ mw2, const float* __restrict__ mb2,
                           const float* __restrict__ mw3, const float* __restrict__ mb3,
                           float* __restrict__ wsf)
{
    const int tid = threadIdx.x;
    if (tid < F_) {
        const int f = tid;
        float Qm[4][4];
        for (int g = 0; g < 4; ++g) {
            float s = 0.f;
            for (int l = 0; l < 4; ++l) s += fabsf(Qp[f * 16 + g * 4 + l]);
            float d = fmaxf(s, 1.0f);
            for (int l = 0; l < 4; ++l) Qm[g][l] = Qp[f * 16 + g * 4 + l] / d;
        }
        double A[4][4];
        for (int i = 0; i < 4; ++i)
            for (int j = 0; j < 4; ++j) {
                double s = 0.0;
                for (int g = 0; g < 4; ++g) s += (double)Qm[g][i] * (double)Qm[g][j];
                A[i][j] = s;
            }
        double M[4][4];
        for (int i = 0; i < 4; ++i) for (int j = 0; j < 4; ++j) M[i][j] = A[i][j];
        for (int it = 0; it < 30; ++it) {
            double T[4][4]; double mx = 0.0;
            for (int i = 0; i < 4; ++i)
                for (int j = 0; j < 4; ++j) {
                    double s = 0.0;
                    for (int k = 0; k < 4; ++k) s += M[i][k] * M[k][j];
                    T[i][j] = s;
                    double a = fabs(s); if (a > mx) mx = a;
                }
            if (mx < 1e-300) break;
            double inv = 1.0 / mx;
            for (int i = 0; i < 4; ++i) for (int j = 0; j < 4; ++j) M[i][j] = T[i][j] * inv;
        }
        int jb = 0; double bn = -1.0;
        for (int j = 0; j < 4; ++j) {
            double nn = 0.0;
            for (int i = 0; i < 4; ++i) nn += M[i][j] * M[i][j];
            if (nn > bn) { bn = nn; jb = j; }
        }
        double v[4]; for (int i = 0; i < 4; ++i) v[i] = M[i][jb];
        double Av[4];
        for (int i = 0; i < 4; ++i) {
            double s = 0.0;
            for (int j = 0; j < 4; ++j) s += A[i][j] * v[j];
            Av[i] = s;
        }
        double vv = 0.0, vav = 0.0;
        for (int i = 0; i < 4; ++i) { vv += v[i] * v[i]; vav += v[i] * Av[i]; }
        float lamf = (float)((vv > 0.0) ? (vav / vv) : 0.0);
        float tau = expf(fmaxf(taus_p[f], 0.0f));
        float qsv = SCALE_C / tau;
        for (int l = 0; l < 4; ++l)
            for (int g = 0; g < 4; ++g)
                wsf[QEQN_F + f * 32 + l * 4 + g] = qsv * Qm[l][g] / lamf;
        for (int g = 0; g < 4; ++g)
            for (int l = 0; l < 4; ++l)
                wsf[QEQN_F + f * 32 + 16 + g * 4 + l] = SCALE_C * Qm[g][l];
    }
    if (tid >= 48 && tid < 50) {
        const int b = tid - 48;
        float lamb_e = expf(lamb[0]);
        float sg = sigma[b];
        float t = sg * 20.0f - 2.0f;
        float h1[F_], h2[F_];
        for (int j = 0; j < F_; ++j) h1[j] = fmaxf(t * mw1[j] + mb1[j], 0.0f);
        for (int j = 0; j < F_; ++j) {
            float s = mb2[j];
            for (int k = 0; k < F_; ++k) s += h1[k] * mw2[k * F_ + j];
            h2[j] = fmaxf(s, 0.0f);
        }
        for (int j = 0; j < F_; ++j) {
            float s = mb3[j];
            for (int k = 0; k < F_; ++k) s += h2[k] * mw3[k * F_ + j];
            float sc = fmaxf(s * 0.05f + sg, 0.0f) + 1e-9f;
            wsf[SINV_F + b * F_ + j] = 1.0f / sc;
            wsf[SLAM_F + b * F_ + j] = lamb_e * sc;
        }
    }
    if (tid == 50) {
        float lamb_e = expf(lamb[0]);
        float eps_e = expf(eps_om[0]);
        wsf[MISC_F + 0] = eps_e;
        wsf[MISC_F + 1] = 1.0f / (1.0f + lamb_e * (1.0f + eps_e));
    }
}

// ---------------- setup: fragment packing (grid-parallel; AFTER setup_math) ----------------
__global__ void setup_pack(const float* __restrict__ Wf, float* __restrict__ wsf)
{
    unsigned short* wsu = (unsigned short*)wsf;
    const int gtid = blockIdx.x * TPB + threadIdx.x;
    for (int i = gtid; i < 73728; i += gridDim.x * TPB) {
        if (i < 49152) {
            // pass-1 A frags: 24 mtiles. even = Wf (v-rows), odd = Qeq.Wf (y-rows)
            int j = i & 7, lane = (i >> 3) & 63;
            int t = i >> 9;                // 0..95
            int ks = t & 3, mtile = t >> 2;
            int rt = lane & 15, qq = lane >> 4;
            int c = ks * 32 + qq * 8 + j;
            int ft = mtile >> 1;
            int f = ft * 4 + (rt >> 2);
            int gl = rt & 3;
            float w;
            if ((mtile & 1) == 0) {
                w = Wf[(gl * F_ + f) * C_ + c];
            } else {
                w = 0.f;
                for (int g = 0; g < 4; ++g)
                    w += wsf[QEQN_F + f * 32 + gl * 4 + g] * Wf[(g * F_ + f) * C_ + c];
            }
            _Float16 hv = (_Float16)w;
            wsu[P1_U + ((mtile * 4 + ks) * 64 + lane) * 8 + j] = *(unsigned short*)&hv;
        } else {
            // pass-2 A frags: K=192, Wf^T only
            int ii = i - 49152;
            int j = ii & 7, lane = (ii >> 3) & 63;
            int t = ii >> 9;               // 0..47
            int ks = t % 6, cmt = t / 6;
            int m = lane & 15, qq = lane >> 4;
            int cch = cmt * 16 + m;
            int r = ks * 32 + qq * 8 + j;  // 0..191
            int f = r >> 2, g = r & 3;
            float w = Wf[(g * F_ + f) * C_ + cch];
            _Float16 hv = (_Float16)w;
            wsu[P2_U + ((cmt * 6 + ks) * 64 + lane) * 8 + j] = *(unsigned short*)&hv;
        }
    }
}

// Duchi-form l1-ball projection merged with the Moreau output:
//   theta = max(0, max_k (c_k - 1)/k)   (c_k = sum of k largest |v|)
//   o_g   = sign(v_g) * (eps*|v_g| + relu(|v_g| - theta))  ==  eps*v + proj(v)
__device__ __forceinline__ void actmerge(const float v[4], float eps, float o[4]) {
    float a0 = fabsf(v[0]), a1 = fabsf(v[1]), a2 = fabsf(v[2]), a3 = fabsf(v[3]);
    float lo01 = fminf(a0, a1), hi01 = fmaxf(a0, a1);
    float lo23 = fminf(a2, a3), hi23 = fmaxf(a2, a3);
    float c4 = (a0 + a1) + (a2 + a3);
    float mn1 = fminf(lo01, lo23);
    float mn2 = fminf(fmaxf(lo01, lo23), fminf(hi01, hi23));
    float c1 = fmaxf(hi01, hi23);
    float c3 = c4 - mn1;
    float c2 = c3 - mn2;
    float t1 = c1 - 1.0f;
    float t2 = (c2 - 1.0f) * 0.5f;
    float t3 = (c3 - 1.0f) * (1.0f / 3.0f);
    float t4 = (c4 - 1.0f) * 0.25f;
    float theta = fmaxf(fmaxf(fmaxf(t1, t2), fmaxf(t3, t4)), 0.0f);
    float aa[4] = {a0, a1, a2, a3};
#pragma unroll
    for (int g = 0; g < 4; ++g) {
        float r = fmaf(eps, aa[g], fmaxf(aa[g] - theta, 0.0f));
        o[g] = copysignf(r, v[g]);
    }
}

// ---------------- main: 16-pixel tile, 4 waves/block, 2048 blocks ----------------
// Barrier-domain experiment, correctly bounded this time:
// __launch_bounds__(256, 4) -> VGPR cap 256/4 = 64 (empirical hipcc law:
// cap = 256/min_waves_per_EU; (256,8) capped at 32 and spilled in R9).
// Kernel needs ~60 VGPR -> fits. Occupancy then limited by wave slots:
// 4-wave blocks, 13.8KB LDS, 60 VGPR -> 8 blocks/CU (32 waves/CU) resident,
// with 8 independent barrier domains per CU whose phases interleave.
__global__ __launch_bounds__(MW, 4) void mfoe_main(
    const float* __restrict__ xnoisy,
    const float* __restrict__ wsf,
    float* __restrict__ out,
    const int* __restrict__ n_iter_p)
{
    __shared__ __align__(16) _Float16 sXF[2048];    // [ks(4)][lane(64)][j(8)]
    __shared__ __align__(16) _Float16 sACT[3072];   // [ks(6)][lane(64)][j(8)]
    __shared__ __align__(16) float sQS[F_ * 16];    // SCALE*Qm[g][l] at [f][g*4+l]
    __shared__ __align__(16) float sISL[96];        // [0..47]=invs, [48..95]=slam

    const int tid = threadIdx.x;
    const int lane = tid & 63;
    const int wv = __builtin_amdgcn_readfirstlane(tid >> 6);   // SGPR wave id, 0..3
    const int n = lane & 15;
    const int q = lane >> 4;
    const int blk = blockIdx.x;
    const int b = blk >> 10;                // 1024 blocks per image
    const int pix0 = (blk & 1023) << 4;     // 16 pixels per block

    const float* __restrict__ xin = xnoisy + b * (C_ * HW) + pix0;
    float* __restrict__ oimg = out + b * (C_ * HW) + pix0;
    const unsigned short* __restrict__ wsu = (const unsigned short*)wsf;
    const int niter = *n_iter_p;

    if (niter == 0) {
        for (int i = tid; i < C_ * 16; i += MW) {
            int p = i & 15, c = i >> 4;
            oimg[c * HW + p] = xin[c * HW + p];
        }
        return;
    }

    // stage x -> LDS f16 in fragment order
    for (int i = tid; i < C_ * 16; i += MW) {
        int p = i & 15, c = i >> 4;
        int idx = ((c >> 5) * 64 + ((c >> 3) & 3) * 16 + p) * 8 + (c & 7);
        sXF[idx] = (_Float16)xin[c * HW + p];
    }
    // stage qs (SCALE*Qm) and invs/slam
    for (int i = tid; i < F_ * 16; i += MW)
        sQS[i] = wsf[QEQN_F + (i >> 4) * 32 + 16 + (i & 15)];
    for (int i = tid; i < 96; i += MW) {
        if (i < 48) sISL[i] = wsf[SINV_F + b * F_ + i];
        else        sISL[i] = wsf[SLAM_F + b * F_ + (i - 48)];
    }

    // x_noisy anchor in registers (update layout: cmt = wv*2+jc, pixel n)
    float xnr[8];
#pragma unroll
    for (int jc = 0; jc < 2; ++jc) {
        int cmt = wv * 2 + jc;
#pragma unroll
        for (int l = 0; l < 4; ++l)
            xnr[jc * 4 + l] = xin[(cmt * 16 + q * 4 + l) * HW + n];
    }

    const float eps_e = wsf[MISC_F + 0];
    const float invden = wsf[MISC_F + 1];

    const half8* __restrict__ A1 = (const half8*)wsu;              // P1 frags
    const half8* __restrict__ A2 = (const half8*)(wsu + P2_U);     // P2 frags
    const half8* __restrict__ sXF8 = (const half8*)sXF;
    const half8* __restrict__ sACT8 = (const half8*)sACT;

    for (int it = 0; it < niter; ++it) {
        __syncthreads();   // x ready (and tables on iter 0)
        // ---- pass 1: 12 ft jobs, 3 per wave, low-pressure
#pragma unroll 1
        for (int jj = 0; jj < 3; ++jj) {
            const int ft = wv * 3 + jj;    // 0..11
            floatx4 accv = (floatx4){0.f, 0.f, 0.f, 0.f};
            floatx4 accy = (floatx4){0.f, 0.f, 0.f, 0.f};
#pragma unroll
            for (int ks = 0; ks < 4; ++ks) {
                half8 aV = A1[((ft * 2 + 0) * 4 + ks) * 64 + lane];
                half8 aY = A1[((ft * 2 + 1) * 4 + ks) * 64 + lane];
                half8 bF = sXF8[ks * 64 + lane];
                accv = __builtin_amdgcn_mfma_f32_16x16x32_f16(aV, bF, accv, 0, 0, 0);
                accy = __builtin_amdgcn_mfma_f32_16x16x32_f16(aY, bF, accy, 0, 0, 0);
            }
            // ---- activation: lane owns f = ft*4+q
            const int f = ft * 4 + q;
            const float invs = sISL[f];
            const float slam = sISL[48 + f];
            float qs[16];
#pragma unroll
            for (int k = 0; k < 4; ++k)
                *(floatx4*)&qs[4 * k] = *(const floatx4*)&sQS[f * 16 + 4 * k];
            float v[4] = {accv[0] * invs, accv[1] * invs, accv[2] * invs, accv[3] * invs};
            float y[4] = {accy[0] * invs, accy[1] * invs, accy[2] * invs, accy[3] * invs};
            float uv[4]; actmerge(v, eps_e, uv);    // eps*v + proj(v)
            float m2[4]; actmerge(y, eps_e, m2);    // eps*y + proj(y)
            float a0 = (uv[0] - fmaf(qs[0], m2[0], fmaf(qs[4], m2[1],
                        fmaf(qs[8], m2[2], qs[12] * m2[3])))) * slam;
            float a1 = (uv[1] - fmaf(qs[1], m2[0], fmaf(qs[5], m2[1],
                        fmaf(qs[9], m2[2], qs[13] * m2[3])))) * slam;
            float a2 = (uv[2] - fmaf(qs[2], m2[0], fmaf(qs[6], m2[1],
                        fmaf(qs[10], m2[2], qs[14] * m2[3])))) * slam;
            float a3 = (uv[3] - fmaf(qs[3], m2[0], fmaf(qs[7], m2[1],
                        fmaf(qs[11], m2[2], qs[15] * m2[3])))) * slam;
            half4 av4;
            av4[0] = (_Float16)a0;
            av4[1] = (_Float16)a1;
            av4[2] = (_Float16)a2;
            av4[3] = (_Float16)a3;
            // act rows r = ft*16 + q*4 + l -> frag slot
            int aw = ((ft >> 1) * 64 + ((ft & 1) * 2 + (q >> 1)) * 16 + n) * 8 + (q & 1) * 4;
            *(half4*)&sACT[aw] = av4;
        }
        __syncthreads();   // act ready; all pass-1 x reads done
        // ---- pass 2: 2 cmt jobs per wave, K=192
        floatx4 acc20 = (floatx4){0.f, 0.f, 0.f, 0.f};
        floatx4 acc21 = (floatx4){0.f, 0.f, 0.f, 0.f};
        const int cm0 = wv * 2;
#pragma unroll
        for (int ks = 0; ks < 6; ++ks) {
            half8 bA = sACT8[ks * 64 + lane];
            half8 aF0 = A2[((cm0 + 0) * 6 + ks) * 64 + lane];
            half8 aF1 = A2[((cm0 + 1) * 6 + ks) * 64 + lane];
            acc20 = __builtin_amdgcn_mfma_f32_16x16x32_f16(aF0, bA, acc20, 0, 0, 0);
            acc21 = __builtin_amdgcn_mfma_f32_16x16x32_f16(aF1, bA, acc21, 0, 0, 0);
        }
        // ---- update: thread owns (cmt = wv*2+jc, q); x carried in sXF (f16)
        const bool last = (it == niter - 1);
#pragma unroll
        for (int jc = 0; jc < 2; ++jc) {
            floatx4 acc = jc ? acc21 : acc20;
            int cmt = wv * 2 + jc;
            int cb = cmt * 16 + q * 4;
            int xu = ((cmt >> 1) * 64 + ((cmt & 1) * 2 + (q >> 1)) * 16 + n) * 8 + (q & 1) * 4;
            half4 xo4 = *(const half4*)&sXF[xu];
            half4 nx4;
#pragma unroll
            for (int l = 0; l < 4; ++l) {
                float xo = (float)xo4[l];
                float nx = xo - ((xo - xnr[jc * 4 + l]) + acc[l]) * invden;
                nx4[l] = (_Float16)nx;
                if (last) oimg[(cb + l) * HW + n] = nx;
            }
            *(half4*)&sXF[xu] = nx4;
        }
    }
}

extern "C" void kernel_launch(void* const* d_in, const int* in_sizes, int n_in,
                              void* d_out, int out_size, void* d_ws, size_t ws_size,
                              hipStream_t stream) {
    const float* x_noisy = (const float*)d_in[0];
    const float* sigma   = (const float*)d_in[1];
    const float* Qp      = (const float*)d_in[2];
    const float* taus_p  = (const float*)d_in[3];
    const float* lamb    = (const float*)d_in[4];
    const float* eps_om  = (const float*)d_in[5];
    const float* mw1     = (const float*)d_in[6];
    const float* mb1     = (const float*)d_in[7];
    const float* mw2     = (const float*)d_in[8];
    const float* mb2     = (const float*)d_in[9];
    const float* mw3     = (const float*)d_in[10];
    const float* mb3     = (const float*)d_in[11];
    const float* Wf      = (const float*)d_in[12];
    const int*   n_iter  = (const int*)d_in[13];
    float* out = (float*)d_out;
    float* ws  = (float*)d_ws;

    hipLaunchKernelGGL(setup_math, dim3(1), dim3(64), 0, stream,
                       sigma, Qp, taus_p, lamb, eps_om,
                       mw1, mb1, mw2, mb2, mw3, mb3, ws);
    hipLaunchKernelGGL(setup_pack, dim3(192), dim3(TPB), 0, stream, Wf, ws);
    hipLaunchKernelGGL(mfoe_main, dim3(2048), dim3(MW), 0, stream,
                       x_noisy, ws, out, n_iter);
}